// Round 8
// baseline (331.737 us; speedup 1.0000x reference)
//
#include <hip/hip_runtime.h>
#include <hip/hip_bf16.h>

#define M_ROWS 16384
#define N_IN   512
#define N_HID  1024
#define K_TOT  1536   // 512 + 1024
#define N_TOT  4096   // 4 gates * 1024
#define NT     48     // K tiles of BK=32

typedef __attribute__((ext_vector_type(4))) float f32x4;
typedef __attribute__((ext_vector_type(8))) short bf16x8;
typedef __attribute__((ext_vector_type(4))) int   i32x4;

__device__ __forceinline__ ushort f2bf(float f) {
    union { float f; unsigned u; } un; un.f = f;
    unsigned u = un.u;
    u += 0x7fffu + ((u >> 16) & 1u);   // RNE
    return (ushort)(u >> 16);
}

__device__ __forceinline__ bf16x8 as_bf(i32x4 v) {
    union { i32x4 i; bf16x8 b; } u; u.i = v; return u.b;
}

// ---------------- prep kernels ----------------

__global__ void build_A(const float* __restrict__ x, const float* __restrict__ h,
                        ushort* __restrict__ A) {
    const int total = M_ROWS * K_TOT / 4;
    for (int p = blockIdx.x * blockDim.x + threadIdx.x; p < total;
         p += gridDim.x * blockDim.x) {
        int flat = p * 4;
        int row = flat / K_TOT;
        int col = flat - row * K_TOT;
        const float* src = (col < N_IN)
            ? (x + (size_t)row * N_IN + col)
            : (h + (size_t)row * N_HID + (col - N_IN));
        float4 v = *(const float4*)src;
        ushort4 o;
        o.x = f2bf(v.x); o.y = f2bf(v.y); o.z = f2bf(v.z); o.w = f2bf(v.w);
        *(ushort4*)(A + flat) = o;
    }
}

// W_perm row p: bn = p>>8 (256 rows per block-col), wcn = (p>>6)&3,
// gate g = (p>>4)&3, u = p&15.  source row j = bn*64 + wcn*16 + u of gate g.
__global__ void build_W(const float* __restrict__ Wii, const float* __restrict__ Wif,
                        const float* __restrict__ Wig, const float* __restrict__ Wio,
                        const float* __restrict__ Whi, const float* __restrict__ Whf,
                        const float* __restrict__ Whg, const float* __restrict__ Who,
                        ushort* __restrict__ Wp) {
    const int total = N_TOT * K_TOT / 4;
    for (int p = blockIdx.x * blockDim.x + threadIdx.x; p < total;
         p += gridDim.x * blockDim.x) {
        int flat = p * 4;
        int prow = flat / K_TOT;
        int col = flat - prow * K_TOT;
        int bn  = prow >> 8;
        int r   = prow & 255;
        int wcn = r >> 6;
        int g   = (r >> 4) & 3;
        int u   = r & 15;
        int j   = bn * 64 + wcn * 16 + u;
        const float* src;
        if (col < N_IN) {
            const float* Wx = (g == 0) ? Wii : (g == 1) ? Wif : (g == 2) ? Wig : Wio;
            src = Wx + (size_t)j * N_IN + col;
        } else {
            const float* Wh = (g == 0) ? Whi : (g == 1) ? Whf : (g == 2) ? Whg : Who;
            src = Wh + (size_t)j * N_HID + (col - N_IN);
        }
        float4 v = *(const float4*)src;
        ushort4 o;
        o.x = f2bf(v.x); o.y = f2bf(v.y); o.z = f2bf(v.z); o.w = f2bf(v.w);
        *(ushort4*)(Wp + flat) = o;
    }
}

__global__ void build_bias(const float* __restrict__ bii, const float* __restrict__ bif,
                           const float* __restrict__ big, const float* __restrict__ bio,
                           const float* __restrict__ bhi, const float* __restrict__ bhf,
                           const float* __restrict__ bhg, const float* __restrict__ bho,
                           float* __restrict__ bias) {
    int n = blockIdx.x * blockDim.x + threadIdx.x;
    if (n >= N_TOT) return;
    int g = n >> 10, j = n & 1023;
    const float* bx = (g == 0) ? bii : (g == 1) ? bif : (g == 2) ? big : bio;
    const float* bh = (g == 0) ? bhi : (g == 1) ? bhf : (g == 2) ? bhg : bho;
    bias[n] = bx[j] + bh[j];
}

// ---------------- GEMM: A via LDS, B direct global->VGPR ----------------
// 256x256 block, BK=32, 8 waves (2M x 4N), per-wave 128x64.
// A: 4 LDS buffers (64 KB), rotate reads one tile ahead (R7 scheme, asm
// ds_read + counted lgkmcnt(8)). B: W_perm panel is L2-resident; each wave
// loads its 4 B-frags/tile straight to VGPRs (asm global_load_dwordx4),
// issued 2 tiles ahead into rotate-2 registers. Removes all B LDS traffic
// (32 ds_reads + 16 KB writes per CU-tile) -> DS pipe (~900 cyc) drops
// below MFMA pipe (~1242 cyc).
// vmcnt ledger: 6 VMEM/tile (2 stage + 4 B); VMC(6) at tile end retires the
// previous tile's batch {stage(t+2), B(t+1)}. Prologue 14 issued, VMC(4).

__device__ __forceinline__ float sigmoid_f(float z) {
    return 1.f / (1.f + __expf(-z));
}
__device__ __forceinline__ float tanh_f(float z) {
    z = fminf(fmaxf(z, -15.f), 15.f);
    float e = __expf(2.f * z);
    return (e - 1.f) / (e + 1.f);
}

__global__ __launch_bounds__(512, 2) void lstm_gemm(
        const ushort* __restrict__ A, const ushort* __restrict__ W,
        const float* __restrict__ bias, const float* __restrict__ cin,
        float* __restrict__ outc, float* __restrict__ outh) {
    __shared__ ushort sA[4][256 * 32];   // 4 x 16 KB = 64 KB

    const int tid  = threadIdx.x;
    const int wid  = tid >> 6;
    const int lane = tid & 63;
    const int wr  = wid >> 2;    // 0..1  M half
    const int wcn = wid & 3;     // 0..3  N quarter (64 cols)
    const int m0 = blockIdx.x * 256;
    const int n0 = blockIdx.y * 256;

    f32x4 acc[8][4] = {};

    // A staging: row = tid>>2 (0..127), global chunk = (tid&3)^((tid>>3)&3),
    // call i adds 128 rows. LDS dst = tid*8 ushorts (+4096 for call 1).
    const int srow = tid >> 2;
    const int fch  = (tid & 3) ^ ((tid >> 3) & 3);
    const ushort* gA = A + (size_t)(m0 + srow) * K_TOT + fch * 8;

#define GLDS(gptr, lptr) __builtin_amdgcn_global_load_lds(                     \
        (const __attribute__((address_space(1))) void*)(gptr),                 \
        (__attribute__((address_space(3))) void*)(lptr), 16, 0, 0)

#define STAGE(db, kt) do {                                                     \
    GLDS(gA + (size_t)(kt) * 32,                       &sA[db][tid * 8]);      \
    GLDS(gA + (size_t)128 * K_TOT + (size_t)(kt) * 32, &sA[db][4096 + tid * 8]); \
} while (0)

    const int lrow = lane & 15;
    const int cb0  = lane >> 4;             // 0..3 k-chunk
    const int csw2 = (lrow >> 1) & 3;       // read-side swizzle (validated R6/R7)
    const unsigned aByte = (unsigned)(((wr * 128 + lrow) * 32 + ((cb0 ^ csw2) * 8)) * 2);

    // B global base: lane covers col (n0 + wcn*64 + nn*16 + lrow), k-chunk cb0
    const uintptr_t wBase = (uintptr_t)(W + (size_t)(n0 + wcn * 64 + lrow) * K_TOT + cb0 * 8);

#define DSR(dst, addr, IMM) asm volatile(                                      \
    "ds_read_b128 %0, %1 offset:" IMM : "=&v"(dst) : "v"(addr))

#define READS(afX, db) do {                                                    \
    unsigned aAd = (unsigned)(uintptr_t)                                       \
        (__attribute__((address_space(3))) ushort*)&sA[db][0] + aByte;         \
    i32x4 r0, r1, r2, r3, r4, r5, r6, r7;                                      \
    DSR(r0, aAd, "0");    DSR(r1, aAd, "1024");                                \
    DSR(r2, aAd, "2048"); DSR(r3, aAd, "3072");                                \
    DSR(r4, aAd, "4096"); DSR(r5, aAd, "5120");                                \
    DSR(r6, aAd, "6144"); DSR(r7, aAd, "7168");                                \
    afX[0] = as_bf(r0); afX[1] = as_bf(r1); afX[2] = as_bf(r2);                \
    afX[3] = as_bf(r3); afX[4] = as_bf(r4); afX[5] = as_bf(r5);                \
    afX[6] = as_bf(r6); afX[7] = as_bf(r7);                                    \
} while (0)

// 4 B-frags for tile kt -> bfX registers (global, invisible to compiler waits)
#define BLOAD(bfX, kt) do {                                                    \
    i32x4 b0_, b1_, b2_, b3_;                                                  \
    uint64_t a0_ = (uint64_t)(wBase + (size_t)(kt) * 64);                      \
    uint64_t a1_ = a0_ + 49152u;                                               \
    uint64_t a2_ = a0_ + 98304u;                                               \
    uint64_t a3_ = a0_ + 147456u;                                              \
    asm volatile("global_load_dwordx4 %0, %1, off" : "=v"(b0_) : "v"(a0_));    \
    asm volatile("global_load_dwordx4 %0, %1, off" : "=v"(b1_) : "v"(a1_));    \
    asm volatile("global_load_dwordx4 %0, %1, off" : "=v"(b2_) : "v"(a2_));    \
    asm volatile("global_load_dwordx4 %0, %1, off" : "=v"(b3_) : "v"(a3_));    \
    bfX[0] = as_bf(b0_); bfX[1] = as_bf(b1_);                                  \
    bfX[2] = as_bf(b2_); bfX[3] = as_bf(b3_);                                  \
} while (0)

#define WAITK(n) do {                                                          \
    asm volatile("s_waitcnt lgkmcnt(" #n ")");                                 \
    __builtin_amdgcn_sched_barrier(0);                                         \
} while (0)

#define MFMAS(afX, bfX) do {                                                   \
    __builtin_amdgcn_s_setprio(1);                                             \
    _Pragma("unroll")                                                          \
    for (int m = 0; m < 8; ++m)                                                \
        _Pragma("unroll")                                                      \
        for (int n = 0; n < 4; ++n)                                            \
            acc[m][n] = __builtin_amdgcn_mfma_f32_16x16x32_bf16(               \
                afX[m], bfX[n], acc[m][n], 0, 0, 0);                           \
    __builtin_amdgcn_s_setprio(0);                                             \
} while (0)

#define BARX() __builtin_amdgcn_s_barrier()
#define VMC(n) asm volatile("s_waitcnt vmcnt(" #n ")" ::: "memory")

    bf16x8 af0[8], af1[8], bfr0[4], bfr1[4];

    // prologue: stage A tiles 0,1,2 (6 loads); load B(0),B(1) (8 loads)
    STAGE(0, 0); STAGE(1, 1); STAGE(2, 2);
    BLOAD(bfr0, 0); BLOAD(bfr1, 1);
    VMC(4);                 // retire S0,S1,S2,B0 (B1 may remain)
    __builtin_amdgcn_sched_barrier(0);
    BARX();
    READS(af0, 0);          // tile-0 A frags

    // tile t: STAGE(t+3) | READS_A(t+1) | lgkm(8) | MFMA(t) | BLOAD(t+2) |
    //         VMC(6) | BAR
#define TILE(u, t, Fna, Fca, Bc) do {                                          \
    STAGE(((u) + 3) & 3, (t) + 3);                                             \
    READS(Fna, ((u) + 1) & 3);                                                 \
    WAITK(8);                                                                  \
    MFMAS(Fca, Bc);                                                            \
    BLOAD(Bc, (t) + 2);                                                        \
    VMC(6);                                                                    \
    BARX();                                                                    \
} while (0)

    for (int hh = 0; hh < 11; ++hh) {
        const int t = hh * 4;
        TILE(0, t + 0, af1, af0, bfr0);
        TILE(1, t + 1, af0, af1, bfr1);
        TILE(2, t + 2, af1, af0, bfr0);
        TILE(3, t + 3, af0, af1, bfr1);
    }
    // t = 44 (u=0): stages 47, loads B(46)
    TILE(0, 44, af1, af0, bfr0);
    // t = 45: no stage; READS(46)=buf2; MFMA(45); BLOAD B(47); VMC(4) retires
    // {S47, B46}; BAR
    READS(af0, 2);
    WAITK(8);
    MFMAS(af1, bfr1);
    BLOAD(bfr1, 47);
    VMC(4);
    BARX();
    // t = 46: READS(47)=buf3; MFMA(46); VMC(0) retires B(47); BAR
    READS(af1, 3);
    WAITK(8);
    MFMAS(af0, bfr0);
    VMC(0);
    BARX();
    // t = 47
    WAITK(0);
    MFMAS(af1, bfr1);

    // epilogue: lane owns unit = bn*64 + wcn*16 + lrow; gates = acc[m][0..3]
    const int unit = blockIdx.y * 64 + wcn * 16 + lrow;
    const float b0 = bias[unit];
    const float b1 = bias[1024 + unit];
    const float b2 = bias[2048 + unit];
    const float b3 = bias[3072 + unit];
    const int r0 = m0 + wr * 128 + (lane >> 4) * 4;
#pragma unroll
    for (int mi = 0; mi < 8; ++mi) {
#pragma unroll
        for (int q = 0; q < 4; ++q) {
            const int row = r0 + mi * 16 + q;
            const size_t off = (size_t)row * N_HID + unit;
            float zi = acc[mi][0][q] + b0;
            float zf = acc[mi][1][q] + b1;
            float zg = acc[mi][2][q] + b2;
            float zo = acc[mi][3][q] + b3;
            float it_ = sigmoid_f(zi);
            float ft = sigmoid_f(zf);
            float gt = tanh_f(zg);
            float ot = sigmoid_f(zo);
            float ct = ft * cin[off] + it_ * gt;
            float ht = ot * tanh_f(ct);
            outc[off] = ct;
            outh[off] = ht;
        }
    }
#undef GLDS
#undef STAGE
#undef DSR
#undef READS
#undef BLOAD
#undef WAITK
#undef MFMAS
#undef BARX
#undef VMC
#undef TILE
}

// ---------------- launch ----------------

extern "C" void kernel_launch(void* const* d_in, const int* in_sizes, int n_in,
                              void* d_out, int out_size, void* d_ws, size_t ws_size,
                              hipStream_t stream) {
    const float* x = (const float*)d_in[0];
    const float* c = (const float*)d_in[1];
    const float* h = (const float*)d_in[2];
    const float* Wii = (const float*)d_in[3];  const float* bii = (const float*)d_in[4];
    const float* Wif = (const float*)d_in[5];  const float* bif = (const float*)d_in[6];
    const float* Wig = (const float*)d_in[7];  const float* big = (const float*)d_in[8];
    const float* Wio = (const float*)d_in[9];  const float* bio = (const float*)d_in[10];
    const float* Whi = (const float*)d_in[11]; const float* bhi = (const float*)d_in[12];
    const float* Whf = (const float*)d_in[13]; const float* bhf = (const float*)d_in[14];
    const float* Whg = (const float*)d_in[15]; const float* bhg = (const float*)d_in[16];
    const float* Who = (const float*)d_in[17]; const float* bho = (const float*)d_in[18];

    char* ws = (char*)d_ws;
    ushort* A_cat  = (ushort*)ws;                                   // 50,331,648 B
    ushort* W_perm = (ushort*)(ws + (size_t)M_ROWS * K_TOT * 2);    // 12,582,912 B
    float*  biasc  = (float*)(ws + (size_t)M_ROWS * K_TOT * 2
                                 + (size_t)N_TOT * K_TOT * 2);      // 16 KB

    float* outc = (float*)d_out;
    float* outh = (float*)d_out + (size_t)M_ROWS * N_HID;

    hipLaunchKernelGGL(build_A, dim3(2048), dim3(256), 0, stream, x, h, A_cat);
    hipLaunchKernelGGL(build_W, dim3(1024), dim3(256), 0, stream,
                       Wii, Wif, Wig, Wio, Whi, Whf, Whg, Who, W_perm);
    hipLaunchKernelGGL(build_bias, dim3(16), dim3(256), 0, stream,
                       bii, bif, big, bio, bhi, bhf, bhg, bho, biasc);
    hipLaunchKernelGGL(lstm_gemm, dim3(M_ROWS / 256, N_TOT / 256), dim3(512), 0, stream,
                       A_cat, W_perm, biasc, c, outc, outh);
}

// Round 9
// 295.408 us; speedup vs baseline: 1.1230x; 1.1230x over previous
//
#include <hip/hip_runtime.h>
#include <hip/hip_bf16.h>

#define M_ROWS 16384
#define N_IN   512
#define N_HID  1024
#define K_TOT  1536   // 512 + 1024
#define N_TOT  4096   // 4 gates * 1024
#define NT     48     // K tiles of BK=32

typedef __attribute__((ext_vector_type(16))) float f32x16;
typedef __attribute__((ext_vector_type(8)))  short bf16x8;
typedef __attribute__((ext_vector_type(4)))  int   i32x4;

__device__ __forceinline__ ushort f2bf(float f) {
    union { float f; unsigned u; } un; un.f = f;
    unsigned u = un.u;
    u += 0x7fffu + ((u >> 16) & 1u);   // RNE
    return (ushort)(u >> 16);
}

__device__ __forceinline__ bf16x8 as_bf(i32x4 v) {
    union { i32x4 i; bf16x8 b; } u; u.i = v; return u.b;
}

// ---------------- prep kernels ----------------

__global__ void build_A(const float* __restrict__ x, const float* __restrict__ h,
                        ushort* __restrict__ A) {
    const int total = M_ROWS * K_TOT / 4;
    for (int p = blockIdx.x * blockDim.x + threadIdx.x; p < total;
         p += gridDim.x * blockDim.x) {
        int flat = p * 4;
        int row = flat / K_TOT;
        int col = flat - row * K_TOT;
        const float* src = (col < N_IN)
            ? (x + (size_t)row * N_IN + col)
            : (h + (size_t)row * N_HID + (col - N_IN));
        float4 v = *(const float4*)src;
        ushort4 o;
        o.x = f2bf(v.x); o.y = f2bf(v.y); o.z = f2bf(v.z); o.w = f2bf(v.w);
        *(ushort4*)(A + flat) = o;
    }
}

// W_perm row p (32x32 gate-tiled): bn = p>>8, r = p&255, wc = r>>7,
// g = (r>>5)&3, u = r&31.  source row j = bn*64 + wc*32 + u of gate g.
// k<512 -> Wx_g else Wh_g.
__global__ void build_W(const float* __restrict__ Wii, const float* __restrict__ Wif,
                        const float* __restrict__ Wig, const float* __restrict__ Wio,
                        const float* __restrict__ Whi, const float* __restrict__ Whf,
                        const float* __restrict__ Whg, const float* __restrict__ Who,
                        ushort* __restrict__ Wp) {
    const int total = N_TOT * K_TOT / 4;
    for (int p = blockIdx.x * blockDim.x + threadIdx.x; p < total;
         p += gridDim.x * blockDim.x) {
        int flat = p * 4;
        int prow = flat / K_TOT;
        int col = flat - prow * K_TOT;
        int bn  = prow >> 8;
        int r   = prow & 255;
        int wc  = r >> 7;
        int g   = (r >> 5) & 3;
        int u   = r & 31;
        int j   = bn * 64 + wc * 32 + u;
        const float* src;
        if (col < N_IN) {
            const float* Wx = (g == 0) ? Wii : (g == 1) ? Wif : (g == 2) ? Wig : Wio;
            src = Wx + (size_t)j * N_IN + col;
        } else {
            const float* Wh = (g == 0) ? Whi : (g == 1) ? Whf : (g == 2) ? Whg : Who;
            src = Wh + (size_t)j * N_HID + (col - N_IN);
        }
        float4 v = *(const float4*)src;
        ushort4 o;
        o.x = f2bf(v.x); o.y = f2bf(v.y); o.z = f2bf(v.z); o.w = f2bf(v.w);
        *(ushort4*)(Wp + flat) = o;
    }
}

__global__ void build_bias(const float* __restrict__ bii, const float* __restrict__ bif,
                           const float* __restrict__ big, const float* __restrict__ bio,
                           const float* __restrict__ bhi, const float* __restrict__ bhf,
                           const float* __restrict__ bhg, const float* __restrict__ bho,
                           float* __restrict__ bias) {
    int n = blockIdx.x * blockDim.x + threadIdx.x;
    if (n >= N_TOT) return;
    int g = n >> 10, j = n & 1023;
    const float* bx = (g == 0) ? bii : (g == 1) ? bif : (g == 2) ? big : bio;
    const float* bh = (g == 0) ? bhi : (g == 1) ? bhf : (g == 2) ? bhg : bho;
    bias[n] = bx[j] + bh[j];
}

// ---------------- 32x32-MFMA rotated-pipeline GEMM + LSTM epilogue --------
// R7 skeleton (4 LDS bufs, rotate read-ahead, counted lgkm, vmcnt(4) ledger)
// with mfma_f32_32x32x16_bf16: 16 MFMA/wave-tile instead of 32 (same FLOPs,
// 2495 vs 2075 TF ubench pipe rate, half the issue slots).
// Waves 4M x 2N; per-wave 64 x 128; gates = the 4 n-tiles of 32 cols.
// C/D map (m74/m101): col=lane&31, row=(reg&3)+8*(reg>>2)+4*(lane>>5).
// Frag reads: lane reads row (lane&31), chunk kh*2+(lane>>5), swizzle
// chunk ^ ((row>>1)&3)  (same stored involution as R6/R7).

__device__ __forceinline__ float sigmoid_f(float z) {
    return 1.f / (1.f + __expf(-z));
}
__device__ __forceinline__ float tanh_f(float z) {
    z = fminf(fmaxf(z, -15.f), 15.f);
    float e = __expf(2.f * z);
    return (e - 1.f) / (e + 1.f);
}

__global__ __launch_bounds__(512, 1) void lstm_gemm(
        const ushort* __restrict__ A, const ushort* __restrict__ W,
        const float* __restrict__ bias, const float* __restrict__ cin,
        float* __restrict__ outc, float* __restrict__ outh) {
    __shared__ ushort sA[4][256 * 32];   // 4 x 16 KB
    __shared__ ushort sB[4][256 * 32];   // 4 x 16 KB  (128 KB total)

    const int tid  = threadIdx.x;
    const int wid  = tid >> 6;
    const int lane = tid & 63;
    const int wr  = wid >> 1;    // 0..3  M quarter (64 rows)
    const int wc  = wid & 1;     // 0..1  N half (128 cols = 4 gates x 32)
    const int m0 = blockIdx.x * 256;
    const int n0 = blockIdx.y * 256;

    f32x16 acc[2][4] = {};

    // staging (unchanged, validated): row = tid>>2, global chunk =
    // (tid&3)^((tid>>3)&3); call i adds 128 rows.
    const int srow = tid >> 2;
    const int fch  = (tid & 3) ^ ((tid >> 3) & 3);
    const ushort* gA = A + (size_t)(m0 + srow) * K_TOT + fch * 8;
    const ushort* gB = W + (size_t)(n0 + srow) * K_TOT + fch * 8;

#define GLDS(gptr, lptr) __builtin_amdgcn_global_load_lds(                     \
        (const __attribute__((address_space(1))) void*)(gptr),                 \
        (__attribute__((address_space(3))) void*)(lptr), 16, 0, 0)

#define STAGE(db, kt) do {                                                     \
    GLDS(gA + (size_t)(kt) * 32,                       &sA[db][tid * 8]);      \
    GLDS(gA + (size_t)128 * K_TOT + (size_t)(kt) * 32, &sA[db][4096 + tid * 8]); \
    GLDS(gB + (size_t)(kt) * 32,                       &sB[db][tid * 8]);      \
    GLDS(gB + (size_t)128 * K_TOT + (size_t)(kt) * 32, &sB[db][4096 + tid * 8]); \
} while (0)

    // frag read addressing
    const int r31 = lane & 31;
    const int khl = lane >> 5;              // 0..1 k-half-lane
    const int csw = (r31 >> 1) & 3;         // read-side swizzle
    // byte offsets within a buffer (row*64B + swizzled-chunk*16B)
    const unsigned aOff0 = (unsigned)((wr * 64  + r31) * 64 + ((0 * 2 + khl) ^ csw) * 16);
    const unsigned aOff1 = (unsigned)((wr * 64  + r31) * 64 + ((1 * 2 + khl) ^ csw) * 16);
    const unsigned bOff0 = (unsigned)((wc * 128 + r31) * 64 + ((0 * 2 + khl) ^ csw) * 16);
    const unsigned bOff1 = (unsigned)((wc * 128 + r31) * 64 + ((1 * 2 + khl) ^ csw) * 16);

#define DSR(dst, addr, IMM) asm volatile(                                      \
    "ds_read_b128 %0, %1 offset:" IMM : "=&v"(dst) : "v"(addr))

// 12 asm ds_reads: A frags [mi][kh] (mi imm = mi*32*64=2048), B frags
// [g][kh] (g imm = g*32*64=2048*g)
#define READS(afX, bfX, db) do {                                               \
    unsigned aB_ = (unsigned)(uintptr_t)                                       \
        (__attribute__((address_space(3))) ushort*)&sA[db][0];                 \
    unsigned bB_ = (unsigned)(uintptr_t)                                       \
        (__attribute__((address_space(3))) ushort*)&sB[db][0];                 \
    unsigned a0_ = aB_ + aOff0, a1_ = aB_ + aOff1;                             \
    unsigned b0_ = bB_ + bOff0, b1_ = bB_ + bOff1;                             \
    DSR(afX[0][0], a0_, "0");  DSR(afX[1][0], a0_, "2048");                    \
    DSR(afX[0][1], a1_, "0");  DSR(afX[1][1], a1_, "2048");                    \
    DSR(bfX[0][0], b0_, "0");  DSR(bfX[1][0], b0_, "2048");                    \
    DSR(bfX[2][0], b0_, "4096"); DSR(bfX[3][0], b0_, "6144");                  \
    DSR(bfX[0][1], b1_, "0");  DSR(bfX[1][1], b1_, "2048");                    \
    DSR(bfX[2][1], b1_, "4096"); DSR(bfX[3][1], b1_, "6144");                  \
} while (0)

#define WAITK(n) do {                                                          \
    asm volatile("s_waitcnt lgkmcnt(" #n ")");                                 \
    __builtin_amdgcn_sched_barrier(0);                                         \
} while (0)

// 16 MFMAs; kh=0 pass then kh=1 pass (dependency distance 8)
#define MFMAS(afX, bfX) do {                                                   \
    __builtin_amdgcn_s_setprio(1);                                             \
    _Pragma("unroll")                                                          \
    for (int mi = 0; mi < 2; ++mi)                                             \
        _Pragma("unroll")                                                      \
        for (int g = 0; g < 4; ++g)                                            \
            acc[mi][g] = __builtin_amdgcn_mfma_f32_32x32x16_bf16(              \
                as_bf(afX[mi][0]), as_bf(bfX[g][0]), acc[mi][g], 0, 0, 0);     \
    _Pragma("unroll")                                                          \
    for (int mi = 0; mi < 2; ++mi)                                             \
        _Pragma("unroll")                                                      \
        for (int g = 0; g < 4; ++g)                                            \
            acc[mi][g] = __builtin_amdgcn_mfma_f32_32x32x16_bf16(              \
                as_bf(afX[mi][1]), as_bf(bfX[g][1]), acc[mi][g], 0, 0, 0);     \
    __builtin_amdgcn_s_setprio(0);                                             \
} while (0)

#define BARX() __builtin_amdgcn_s_barrier()
#define VMC(n) asm volatile("s_waitcnt vmcnt(" #n ")" ::: "memory")

    i32x4 af0[2][2], bf0[4][2], af1[2][2], bf1[4][2];

    // prologue: stage tiles 0,1,2; retire 0,1; read tile-0 frags
    STAGE(0, 0); STAGE(1, 1); STAGE(2, 2);
    VMC(4);
    BARX();
    READS(af0, bf0, 0);

    // tile t: STAGE(t+3) | READS(t+1) | lgkm(12) | MFMA(t) | VMC(4) | BAR
#define TILE(u, t, FnA, FnB, FcA, FcB) do {                                    \
    STAGE(((u) + 3) & 3, (t) + 3);                                             \
    READS(FnA, FnB, ((u) + 1) & 3);                                            \
    WAITK(12);                                                                 \
    MFMAS(FcA, FcB);                                                           \
    VMC(4);                                                                    \
    BARX();                                                                    \
} while (0)

    for (int hh = 0; hh < 11; ++hh) {
        const int t = hh * 4;
        TILE(0, t + 0, af1, bf1, af0, bf0);
        TILE(1, t + 1, af0, bf0, af1, bf1);
        TILE(2, t + 2, af1, bf1, af0, bf0);
        TILE(3, t + 3, af0, bf0, af1, bf1);
    }
    // peeled tail: t = 44..47
    TILE(0, 44, af1, bf1, af0, bf0);            // stages 47
    // t=45: no stage
    READS(af0, bf0, 2);                         // tile 46 frags
    WAITK(12);
    MFMAS(af1, bf1);                            // tile 45
    VMC(0);
    BARX();
    // t=46
    READS(af1, bf1, 3);                         // tile 47 frags
    WAITK(12);
    MFMAS(af0, bf0);                            // tile 46
    BARX();
    // t=47
    WAITK(0);
    MFMAS(af1, bf1);                            // tile 47

    // epilogue: lane owns unit = bn*64 + wc*32 + r31; gates = acc[mi][0..3]
    const int unit = blockIdx.y * 64 + wc * 32 + r31;
    const float b0 = bias[unit];
    const float b1 = bias[1024 + unit];
    const float b2 = bias[2048 + unit];
    const float b3 = bias[3072 + unit];
    const int r0 = m0 + wr * 64 + 4 * khl;
#pragma unroll
    for (int mi = 0; mi < 2; ++mi) {
#pragma unroll
        for (int reg = 0; reg < 16; ++reg) {
            const int row = r0 + mi * 32 + (reg & 3) + 8 * (reg >> 2);
            const size_t off = (size_t)row * N_HID + unit;
            float zi = acc[mi][0][reg] + b0;
            float zf = acc[mi][1][reg] + b1;
            float zg = acc[mi][2][reg] + b2;
            float zo = acc[mi][3][reg] + b3;
            float it_ = sigmoid_f(zi);
            float ft = sigmoid_f(zf);
            float gt = tanh_f(zg);
            float ot = sigmoid_f(zo);
            float ct = ft * cin[off] + it_ * gt;
            float ht = ot * tanh_f(ct);
            outc[off] = ct;
            outh[off] = ht;
        }
    }
#undef GLDS
#undef STAGE
#undef DSR
#undef READS
#undef WAITK
#undef MFMAS
#undef BARX
#undef VMC
#undef TILE
}

// ---------------- launch ----------------

extern "C" void kernel_launch(void* const* d_in, const int* in_sizes, int n_in,
                              void* d_out, int out_size, void* d_ws, size_t ws_size,
                              hipStream_t stream) {
    const float* x = (const float*)d_in[0];
    const float* c = (const float*)d_in[1];
    const float* h = (const float*)d_in[2];
    const float* Wii = (const float*)d_in[3];  const float* bii = (const float*)d_in[4];
    const float* Wif = (const float*)d_in[5];  const float* bif = (const float*)d_in[6];
    const float* Wig = (const float*)d_in[7];  const float* big = (const float*)d_in[8];
    const float* Wio = (const float*)d_in[9];  const float* bio = (const float*)d_in[10];
    const float* Whi = (const float*)d_in[11]; const float* bhi = (const float*)d_in[12];
    const float* Whf = (const float*)d_in[13]; const float* bhf = (const float*)d_in[14];
    const float* Whg = (const float*)d_in[15]; const float* bhg = (const float*)d_in[16];
    const float* Who = (const float*)d_in[17]; const float* bho = (const float*)d_in[18];

    char* ws = (char*)d_ws;
    ushort* A_cat  = (ushort*)ws;                                   // 50,331,648 B
    ushort* W_perm = (ushort*)(ws + (size_t)M_ROWS * K_TOT * 2);    // 12,582,912 B
    float*  biasc  = (float*)(ws + (size_t)M_ROWS * K_TOT * 2
                                 + (size_t)N_TOT * K_TOT * 2);      // 16 KB

    float* outc = (float*)d_out;
    float* outh = (float*)d_out + (size_t)M_ROWS * N_HID;

    hipLaunchKernelGGL(build_A, dim3(2048), dim3(256), 0, stream, x, h, A_cat);
    hipLaunchKernelGGL(build_W, dim3(1024), dim3(256), 0, stream,
                       Wii, Wif, Wig, Wio, Whi, Whf, Whg, Who, W_perm);
    hipLaunchKernelGGL(build_bias, dim3(16), dim3(256), 0, stream,
                       bii, bif, big, bio, bhi, bhf, bhg, bho, biasc);
    hipLaunchKernelGGL(lstm_gemm, dim3(M_ROWS / 256, N_TOT / 256), dim3(512), 0, stream,
                       A_cat, W_perm, biasc, c, outc, outh);
}